// Round 4
// baseline (1164.471 us; speedup 1.0000x reference)
//
#include <hip/hip_runtime.h>

#define N_NODES 100000
#define N_EDGES 3200000
#define F_IN 512
#define NH 16
#define F_OUT 128
#define NCLS 3

#define NB 391        // ceil(100000/256) buckets of 256 nodes (key = dst>>8)
#define BCAP 9216     // mean 8184 + ~11 sigma
#define CHUNK 16384   // edges per binning block

typedef float  f32x4 __attribute__((ext_vector_type(4)));
typedef short  s16x8 __attribute__((ext_vector_type(8)));

static __device__ __forceinline__ short f2bf(float f) {
    union { float f; unsigned u; } v; v.f = f;
    unsigned r = v.u + 0x7FFFu + ((v.u >> 16) & 1u);   // RNE
    return (short)(r >> 16);
}

// ---------------- binning: count -> reserve -> scatter (packed src|local_dst) ----------------
// also folds the deg_out (src) histogram.
__global__ __launch_bounds__(512) void bin_kernel(const int* __restrict__ src,
                                                  const int* __restrict__ dst,
                                                  int* __restrict__ deg_out,
                                                  int* __restrict__ gcursor,
                                                  int* __restrict__ pairbuf) {
    __shared__ int hist[NB];
    __shared__ int cur[NB];
    int t = threadIdx.x;
    for (int i = t; i < NB; i += 512) hist[i] = 0;
    __syncthreads();
    int e0 = blockIdx.x * CHUNK;
    int nE = N_EDGES - e0; if (nE > CHUNK) nE = CHUNK;
    // phase 1: count buckets
    for (int i = t; i < nE; i += 512) {
        int d = dst[e0 + i];
        atomicAdd(&hist[d >> 8], 1);
    }
    __syncthreads();
    // reserve (rotate to spread global atomic contention)
    int rot = blockIdx.x % NB;
    for (int j = t; j < NB; j += 512) {
        int b = j + rot; if (b >= NB) b -= NB;
        int h = hist[b];
        cur[b] = (h > 0) ? atomicAdd(&gcursor[b], h) : 0;
    }
    __syncthreads();
    // phase 2: scatter
    for (int i = t; i < nE; i += 512) {
        int s = src[e0 + i];
        int d = dst[e0 + i];
        atomicAdd(&deg_out[s], 1);
        int b = d >> 8;
        int pos = atomicAdd(&cur[b], 1);
        if (pos < BCAP) pairbuf[b * BCAP + pos] = s | ((d & 255) << 17);
    }
}

// ---------------- W1 -> bf16 B-fragment pack ----------------
__global__ void w1b_prep_kernel(const float* __restrict__ W1, unsigned short* __restrict__ W1B) {
    int idx = blockIdx.x * blockDim.x + threadIdx.x;
    if (idx >= 16 * 64 * 8) return;
    int kc = idx >> 9, lane = (idx >> 3) & 63, i = idx & 7;
    int k = kc * 32 + (lane >> 4) * 8 + i;
    int j = lane & 15;
    W1B[idx] = (unsigned short)f2bf(W1[k * NH + j]);
}

// ---------------- Wc = W2 @ Wfc (16x3), bc = b2 @ Wfc + bfc (3) ----------------
__global__ void wc_prep_kernel(const float* __restrict__ W2, const float* __restrict__ b2,
                               const float* __restrict__ Wfc, const float* __restrict__ bfc,
                               float* __restrict__ Wc) {
    int t = threadIdx.x;
    if (t < NH * NCLS) {
        int j = t / NCLS, c = t % NCLS;
        float acc = 0.0f;
        for (int k = 0; k < F_OUT; ++k) acc += W2[j * F_OUT + k] * Wfc[k * NCLS + c];
        Wc[t] = acc;
    } else if (t < NH * NCLS + NCLS) {
        int c = t - NH * NCLS;
        float acc = bfc[c];
        for (int k = 0; k < F_OUT; ++k) acc += b2[k] * Wfc[k * NCLS + c];
        Wc[t] = acc;
    }
}

// ---------------- GEMM1 (MFMA): h1 = (feat @ W1) * norm_src ----------------
__global__ __launch_bounds__(256) void gemm1_kernel(const float* __restrict__ feat,
                                                    const unsigned short* __restrict__ W1B,
                                                    const int* __restrict__ deg_out,
                                                    float* __restrict__ h1) {
    int t = threadIdx.x;
    int lane = t & 63;
    int m = lane & 15;
    int q = lane >> 4;
    const s16x8* wb = (const s16x8*)W1B;
    s16x8 B[16];
#pragma unroll
    for (int kc = 0; kc < 16; ++kc) B[kc] = wb[kc * 64 + lane];

    int w = blockIdx.x * 4 + (t >> 6);
    int nwaves = gridDim.x * 4;
    const int ntiles = N_NODES / 16;   // 6250
    for (int tile = w; tile < ntiles; tile += nwaves) {
        f32x4 acc = {0.0f, 0.0f, 0.0f, 0.0f};
        const float* arow = feat + (size_t)(tile * 16 + m) * F_IN + q * 8;
#pragma unroll
        for (int kc = 0; kc < 16; ++kc) {
            f32x4 fa = *(const f32x4*)(arow + kc * 32);
            f32x4 fb = *(const f32x4*)(arow + kc * 32 + 4);
            s16x8 a;
            a[0] = f2bf(fa.x); a[1] = f2bf(fa.y); a[2] = f2bf(fa.z); a[3] = f2bf(fa.w);
            a[4] = f2bf(fb.x); a[5] = f2bf(fb.y); a[6] = f2bf(fb.z); a[7] = f2bf(fb.w);
            acc = __builtin_amdgcn_mfma_f32_16x16x32_bf16(a, B[kc], acc, 0, 0, 0);
        }
#pragma unroll
        for (int r = 0; r < 4; ++r) {
            int node = tile * 16 + q * 4 + r;
            float ns = rsqrtf(fmaxf((float)deg_out[node], 1.0f));
            h1[(size_t)node * NH + m] = acc[r] * ns;
        }
    }
}

// ---------------- AGG1 (bucket): x1n = relu(nd * sum h1[src] + b1) * ns ----------------
__global__ __launch_bounds__(512) void agg1_bucket_kernel(const int* __restrict__ gcursor,
                                                          const int* __restrict__ pairbuf,
                                                          const float* __restrict__ h1,
                                                          const int* __restrict__ deg_out,
                                                          const float* __restrict__ b1,
                                                          float* __restrict__ x1n) {
    __shared__ float acc[256 * 17];   // stride 17: banks spread by node
    __shared__ int   cnt[256];
    __shared__ float b1s[16];
    int b = blockIdx.x, t = threadIdx.x;
    for (int i = t; i < 256 * 17; i += 512) acc[i] = 0.0f;
    if (t < 256) cnt[t] = 0;
    if (t < 16) b1s[t] = b1[t];
    __syncthreads();
    int c = gcursor[b]; if (c > BCAP) c = BCAP;
    const int* pb = pairbuf + (size_t)b * BCAP;
    int lane = t & 63, w = t >> 6;
    int eo = lane >> 2, comp = lane & 3;
    for (int e0 = w * 16; e0 < c; e0 += 128) {
        int e = e0 + eo;
        if (e < c) {
            int pk = pb[e];
            int s = pk & 0x1FFFF;
            int loc = pk >> 17;
            f32x4 hv = *(const f32x4*)(h1 + (size_t)s * NH + comp * 4);
            int base = loc * 17 + comp * 4;
            atomicAdd(&acc[base + 0], hv.x);
            atomicAdd(&acc[base + 1], hv.y);
            atomicAdd(&acc[base + 2], hv.z);
            atomicAdd(&acc[base + 3], hv.w);
            if (comp == 0) atomicAdd(&cnt[loc], 1);
        }
    }
    __syncthreads();
    int node = b * 256 + t;
    if (t < 256 && node < N_NODES) {
        float nd = rsqrtf(fmaxf((float)cnt[t], 1.0f));
        float ns = rsqrtf(fmaxf((float)deg_out[node], 1.0f));
        f32x4* dstp = (f32x4*)(x1n + (size_t)node * NH);
#pragma unroll
        for (int g = 0; g < 4; ++g) {
            f32x4 v;
            v.x = fmaxf(acc[t * 17 + g * 4 + 0] * nd + b1s[g * 4 + 0], 0.0f) * ns;
            v.y = fmaxf(acc[t * 17 + g * 4 + 1] * nd + b1s[g * 4 + 1], 0.0f) * ns;
            v.z = fmaxf(acc[t * 17 + g * 4 + 2] * nd + b1s[g * 4 + 2], 0.0f) * ns;
            v.w = fmaxf(acc[t * 17 + g * 4 + 3] * nd + b1s[g * 4 + 3], 0.0f) * ns;
            dstp[g] = v;
        }
    }
}

// ---------------- AGG2 (bucket) + tail: out = nd * (sum x1n[src]) @ Wc + bc ----------------
__global__ __launch_bounds__(512) void agg2_bucket_kernel(const int* __restrict__ gcursor,
                                                          const int* __restrict__ pairbuf,
                                                          const float* __restrict__ x1n,
                                                          const float* __restrict__ Wc,
                                                          float* __restrict__ out) {
    __shared__ float acc[256 * 17];
    __shared__ int   cnt[256];
    __shared__ float Wcs[NH * NCLS + NCLS];
    int b = blockIdx.x, t = threadIdx.x;
    for (int i = t; i < 256 * 17; i += 512) acc[i] = 0.0f;
    if (t < 256) cnt[t] = 0;
    if (t < NH * NCLS + NCLS) Wcs[t] = Wc[t];
    __syncthreads();
    int c = gcursor[b]; if (c > BCAP) c = BCAP;
    const int* pb = pairbuf + (size_t)b * BCAP;
    int lane = t & 63, w = t >> 6;
    int eo = lane >> 2, comp = lane & 3;
    for (int e0 = w * 16; e0 < c; e0 += 128) {
        int e = e0 + eo;
        if (e < c) {
            int pk = pb[e];
            int s = pk & 0x1FFFF;
            int loc = pk >> 17;
            f32x4 hv = *(const f32x4*)(x1n + (size_t)s * NH + comp * 4);
            int base = loc * 17 + comp * 4;
            atomicAdd(&acc[base + 0], hv.x);
            atomicAdd(&acc[base + 1], hv.y);
            atomicAdd(&acc[base + 2], hv.z);
            atomicAdd(&acc[base + 3], hv.w);
            if (comp == 0) atomicAdd(&cnt[loc], 1);
        }
    }
    __syncthreads();
    int node = b * 256 + t;
    if (t < 256 && node < N_NODES) {
        float nd = rsqrtf(fmaxf((float)cnt[t], 1.0f));
        float p0 = 0.0f, p1 = 0.0f, p2 = 0.0f;
#pragma unroll
        for (int j = 0; j < NH; ++j) {
            float y = acc[t * 17 + j];
            p0 += y * Wcs[j * NCLS + 0];
            p1 += y * Wcs[j * NCLS + 1];
            p2 += y * Wcs[j * NCLS + 2];
        }
        out[(size_t)node * NCLS + 0] = nd * p0 + Wcs[NH * NCLS + 0];
        out[(size_t)node * NCLS + 1] = nd * p1 + Wcs[NH * NCLS + 1];
        out[(size_t)node * NCLS + 2] = nd * p2 + Wcs[NH * NCLS + 2];
    }
}

// ---------------- launch ----------------
extern "C" void kernel_launch(void* const* d_in, const int* in_sizes, int n_in,
                              void* d_out, int out_size, void* d_ws, size_t ws_size,
                              hipStream_t stream) {
    const float* feat = (const float*)d_in[0];
    const int*   src  = (const int*)d_in[1];
    const int*   dst  = (const int*)d_in[2];
    const float* W1   = (const float*)d_in[3];
    const float* b1   = (const float*)d_in[4];
    const float* W2   = (const float*)d_in[5];
    const float* b2   = (const float*)d_in[6];
    const float* Wfc  = (const float*)d_in[7];
    const float* bfc  = (const float*)d_in[8];
    float* out = (float*)d_out;

    char* ws = (char*)d_ws;
    size_t off = 0;
    auto carve = [&](size_t bytes) {
        char* p = ws + off;
        off = (off + bytes + 255) & ~(size_t)255;
        return p;
    };
    int*   deg_out  = (int*)carve((size_t)N_NODES * 4);
    int*   gcursor  = (int*)carve((size_t)NB * 4);
    int*   pairbuf  = (int*)carve((size_t)NB * BCAP * 4);
    float* h1       = (float*)carve((size_t)N_NODES * NH * 4);
    float* x1n      = (float*)carve((size_t)N_NODES * NH * 4);
    unsigned short* W1B = (unsigned short*)carve(16 * 64 * 8 * 2);
    float* Wc       = (float*)carve((NH * NCLS + NCLS) * 4);
    (void)ws_size;

    hipMemsetAsync(deg_out, 0, (size_t)N_NODES * 4, stream);
    hipMemsetAsync(gcursor, 0, (size_t)NB * 4, stream);

    const int nBinBlocks = (N_EDGES + CHUNK - 1) / CHUNK;   // 196
    bin_kernel<<<nBinBlocks, 512, 0, stream>>>(src, dst, deg_out, gcursor, pairbuf);

    w1b_prep_kernel<<<32, 256, 0, stream>>>(W1, W1B);
    wc_prep_kernel<<<1, 64, 0, stream>>>(W2, b2, Wfc, bfc, Wc);

    gemm1_kernel<<<1250, 256, 0, stream>>>(feat, W1B, deg_out, h1);

    agg1_bucket_kernel<<<NB, 512, 0, stream>>>(gcursor, pairbuf, h1, deg_out, b1, x1n);

    agg2_bucket_kernel<<<NB, 512, 0, stream>>>(gcursor, pairbuf, x1n, Wc, out);
}

// Round 5
// 592.924 us; speedup vs baseline: 1.9639x; 1.9639x over previous
//
#include <hip/hip_runtime.h>

#define N_NODES 100000
#define N_EDGES 3200000
#define F_IN 512
#define NH 16
#define F_OUT 128
#define NCLS 3

#define NB 782        // ceil(100000/128) buckets of 128 nodes (key = dst>>7)
#define BCAP 4736     // mean 4092 + ~10 sigma
#define CHUNK 16384   // edges per binning block

typedef float  f32x4 __attribute__((ext_vector_type(4)));
typedef short  s16x8 __attribute__((ext_vector_type(8)));
typedef unsigned short u16x4 __attribute__((ext_vector_type(4)));

static __device__ __forceinline__ unsigned short f2bf(float f) {
    union { float f; unsigned u; } v; v.f = f;
    unsigned r = v.u + 0x7FFFu + ((v.u >> 16) & 1u);   // RNE
    return (unsigned short)(r >> 16);
}
static __device__ __forceinline__ float bf2f(unsigned short u) {
    union { unsigned u; float f; } v; v.u = ((unsigned)u) << 16;
    return v.f;
}

// ---------------- binning: count -> reserve -> re-read scatter ----------------
// long runs per bucket (CHUNK/NB ~ 21 edges) keep pairbuf lines mostly covered.
// deg_out histogram folded into phase 1.
__global__ __launch_bounds__(512) void bin_kernel(const int* __restrict__ src,
                                                  const int* __restrict__ dst,
                                                  int* __restrict__ deg_out,
                                                  int* __restrict__ gcursor,
                                                  int* __restrict__ pairbuf) {
    __shared__ int hist[NB];
    __shared__ int cur[NB];
    int t = threadIdx.x;
    for (int i = t; i < NB; i += 512) hist[i] = 0;
    __syncthreads();
    int e0 = blockIdx.x * CHUNK;
    int nE = N_EDGES - e0; if (nE > CHUNK) nE = CHUNK;
    for (int i = t; i < nE; i += 512) {
        int s = src[e0 + i];
        int d = dst[e0 + i];
        atomicAdd(&deg_out[s], 1);
        atomicAdd(&hist[d >> 7], 1);
    }
    __syncthreads();
    int rot = blockIdx.x % NB;
    for (int j = t; j < NB; j += 512) {
        int b = j + rot; if (b >= NB) b -= NB;
        int h = hist[b];
        cur[b] = (h > 0) ? atomicAdd(&gcursor[b], h) : 0;
    }
    __syncthreads();
    for (int i = t; i < nE; i += 512) {
        int s = src[e0 + i];
        int d = dst[e0 + i];
        int b = d >> 7;
        int pos = atomicAdd(&cur[b], 1);
        if (pos < BCAP) pairbuf[b * BCAP + pos] = s | ((d & 127) << 17);
    }
}

// ---------------- exclusive scan over bucket counts -> csr bucket bases ----------------
__global__ __launch_bounds__(1024) void bucket_scan_kernel(const int* __restrict__ gcursor,
                                                           int* __restrict__ csr_base) {
    __shared__ int s[1024];
    int t = threadIdx.x;
    int v = 0;
    if (t < NB) { v = gcursor[t]; if (v > BCAP) v = BCAP; }
    s[t] = v;
    __syncthreads();
    for (int off = 1; off < 1024; off <<= 1) {
        int x = (t >= off) ? s[t - off] : 0;
        __syncthreads();
        s[t] += x;
        __syncthreads();
    }
    if (t < NB) csr_base[t] = s[t] - v;
}

// ---------------- per-bucket CSR build + row_ptr + norm_dst ----------------
__global__ __launch_bounds__(256) void bucket_csr_kernel(const int* __restrict__ gcursor,
                                                         const int* __restrict__ csr_base,
                                                         const int* __restrict__ pairbuf,
                                                         int* __restrict__ col,
                                                         int* __restrict__ row_ptr,
                                                         float* __restrict__ norm_dst) {
    __shared__ int hist[128];
    __shared__ int scn[128];
    int b = blockIdx.x;
    int t = threadIdx.x;
    if (t < 128) hist[t] = 0;
    __syncthreads();
    int c = gcursor[b]; if (c > BCAP) c = BCAP;
    const int* pb = pairbuf + (size_t)b * BCAP;
    int pk[19], rk[19];
#pragma unroll
    for (int it = 0; it < 19; ++it) {
        int i = t + it * 256;
        bool valid = i < c;
        int v = valid ? pb[i] : 0;
        pk[it] = v;
        rk[it] = valid ? atomicAdd(&hist[v >> 17], 1) : 0;
    }
    __syncthreads();
    if (t < 128) scn[t] = hist[t];
    __syncthreads();
    for (int off = 1; off < 128; off <<= 1) {
        int x = (t >= off && t < 128) ? scn[t - off] : 0;
        __syncthreads();
        if (t < 128) scn[t] += x;   // inclusive
        __syncthreads();
    }
    int gbase = csr_base[b];
#pragma unroll
    for (int it = 0; it < 19; ++it) {
        int i = t + it * 256;
        if (i < c) {
            int v = pk[it];
            int node = v >> 17;
            int pos = gbase + (scn[node] - hist[node]) + rk[it];
            col[pos] = v & 0x1FFFF;
        }
    }
    int node = b * 128 + t;
    if (t < 128 && node < N_NODES) {
        row_ptr[node] = gbase + scn[t] - hist[t];
        norm_dst[node] = rsqrtf(fmaxf((float)hist[t], 1.0f));
    }
    if (b == NB - 1 && t == 0) row_ptr[N_NODES] = N_EDGES;
}

// ---------------- W1 -> bf16 B-fragment pack ----------------
__global__ void w1b_prep_kernel(const float* __restrict__ W1, unsigned short* __restrict__ W1B) {
    int idx = blockIdx.x * blockDim.x + threadIdx.x;
    if (idx >= 16 * 64 * 8) return;
    int kc = idx >> 9, lane = (idx >> 3) & 63, i = idx & 7;
    int k = kc * 32 + (lane >> 4) * 8 + i;
    int j = lane & 15;
    W1B[idx] = f2bf(W1[k * NH + j]);
}

// ---------------- Wc = W2 @ Wfc (16x3), bc = b2 @ Wfc + bfc (3) ----------------
__global__ void wc_prep_kernel(const float* __restrict__ W2, const float* __restrict__ b2,
                               const float* __restrict__ Wfc, const float* __restrict__ bfc,
                               float* __restrict__ Wc) {
    int t = threadIdx.x;
    if (t < NH * NCLS) {
        int j = t / NCLS, c = t % NCLS;
        float acc = 0.0f;
        for (int k = 0; k < F_OUT; ++k) acc += W2[j * F_OUT + k] * Wfc[k * NCLS + c];
        Wc[t] = acc;
    } else if (t < NH * NCLS + NCLS) {
        int c = t - NH * NCLS;
        float acc = bfc[c];
        for (int k = 0; k < F_OUT; ++k) acc += b2[k] * Wfc[k * NCLS + c];
        Wc[t] = acc;
    }
}

// ---------------- GEMM1 (MFMA): h1b = bf16((feat @ W1) * norm_src) ----------------
__global__ __launch_bounds__(256) void gemm1_kernel(const float* __restrict__ feat,
                                                    const unsigned short* __restrict__ W1B,
                                                    const int* __restrict__ deg_out,
                                                    unsigned short* __restrict__ h1b) {
    int t = threadIdx.x;
    int lane = t & 63;
    int m = lane & 15;
    int q = lane >> 4;
    const s16x8* wb = (const s16x8*)W1B;
    s16x8 B[16];
#pragma unroll
    for (int kc = 0; kc < 16; ++kc) B[kc] = wb[kc * 64 + lane];

    int w = blockIdx.x * 4 + (t >> 6);
    int nwaves = gridDim.x * 4;
    const int ntiles = N_NODES / 16;   // 6250
    for (int tile = w; tile < ntiles; tile += nwaves) {
        f32x4 acc = {0.0f, 0.0f, 0.0f, 0.0f};
        const float* arow = feat + (size_t)(tile * 16 + m) * F_IN + q * 8;
#pragma unroll
        for (int kc = 0; kc < 16; ++kc) {
            f32x4 fa = *(const f32x4*)(arow + kc * 32);
            f32x4 fb = *(const f32x4*)(arow + kc * 32 + 4);
            s16x8 a;
            a[0] = f2bf(fa.x); a[1] = f2bf(fa.y); a[2] = f2bf(fa.z); a[3] = f2bf(fa.w);
            a[4] = f2bf(fb.x); a[5] = f2bf(fb.y); a[6] = f2bf(fb.z); a[7] = f2bf(fb.w);
            acc = __builtin_amdgcn_mfma_f32_16x16x32_bf16(a, B[kc], acc, 0, 0, 0);
        }
#pragma unroll
        for (int r = 0; r < 4; ++r) {
            int node = tile * 16 + q * 4 + r;
            float ns = rsqrtf(fmaxf((float)deg_out[node], 1.0f));
            h1b[(size_t)node * NH + m] = f2bf(acc[r] * ns);
        }
    }
}

// ---------------- AGG1: x1nb = bf16(relu(nd * sum h1[src] + b1) * ns) ----------------
// wave-per-node; 4 lanes x ushort4(8B) per edge row, 16 edges in flight.
__global__ __launch_bounds__(256) void agg1_kernel(const int* __restrict__ row_ptr,
                                                   const int* __restrict__ col,
                                                   const unsigned short* __restrict__ h1b,
                                                   const float* __restrict__ norm_dst,
                                                   const int* __restrict__ deg_out,
                                                   const float* __restrict__ b1,
                                                   unsigned short* __restrict__ x1nb) {
    int t = threadIdx.x;
    int lane = t & 63;
    int n = blockIdx.x * 4 + (t >> 6);
    int eo = lane >> 2, comp = lane & 3;
    int beg = row_ptr[n], end = row_ptr[n + 1];
    f32x4 acc = {0.0f, 0.0f, 0.0f, 0.0f};
    for (int e = beg + eo; e < end; e += 16) {
        int s = col[e];
        u16x4 hv = *(const u16x4*)(h1b + (size_t)s * NH + comp * 4);
        acc.x += bf2f(hv.x); acc.y += bf2f(hv.y);
        acc.z += bf2f(hv.z); acc.w += bf2f(hv.w);
    }
#pragma unroll
    for (int sh = 4; sh <= 32; sh <<= 1) {
        acc.x += __shfl_xor(acc.x, sh); acc.y += __shfl_xor(acc.y, sh);
        acc.z += __shfl_xor(acc.z, sh); acc.w += __shfl_xor(acc.w, sh);
    }
    if (lane < 4) {
        float nd = norm_dst[n];
        float ns = rsqrtf(fmaxf((float)deg_out[n], 1.0f));
        f32x4 bv = ((const f32x4*)b1)[lane];
        f32x4 v = acc * nd + bv;
        u16x4 o;
        o.x = f2bf(fmaxf(v.x, 0.0f) * ns); o.y = f2bf(fmaxf(v.y, 0.0f) * ns);
        o.z = f2bf(fmaxf(v.z, 0.0f) * ns); o.w = f2bf(fmaxf(v.w, 0.0f) * ns);
        *(u16x4*)(x1nb + (size_t)n * NH + lane * 4) = o;
    }
}

// ---------------- AGG2 + tail: out = nd * (sum x1n[src]) @ Wc + bc ----------------
__global__ __launch_bounds__(256) void agg2_kernel(const int* __restrict__ row_ptr,
                                                   const int* __restrict__ col,
                                                   const unsigned short* __restrict__ x1nb,
                                                   const float* __restrict__ norm_dst,
                                                   const float* __restrict__ Wc,
                                                   float* __restrict__ out) {
    __shared__ float Wcs[NH * NCLS + NCLS];
    int t = threadIdx.x;
    if (t < NH * NCLS + NCLS) Wcs[t] = Wc[t];
    __syncthreads();
    int lane = t & 63;
    int n = blockIdx.x * 4 + (t >> 6);
    int eo = lane >> 2, comp = lane & 3;
    int beg = row_ptr[n], end = row_ptr[n + 1];
    f32x4 acc = {0.0f, 0.0f, 0.0f, 0.0f};
    for (int e = beg + eo; e < end; e += 16) {
        int s = col[e];
        u16x4 hv = *(const u16x4*)(x1nb + (size_t)s * NH + comp * 4);
        acc.x += bf2f(hv.x); acc.y += bf2f(hv.y);
        acc.z += bf2f(hv.z); acc.w += bf2f(hv.w);
    }
#pragma unroll
    for (int sh = 4; sh <= 32; sh <<= 1) {
        acc.x += __shfl_xor(acc.x, sh); acc.y += __shfl_xor(acc.y, sh);
        acc.z += __shfl_xor(acc.z, sh); acc.w += __shfl_xor(acc.w, sh);
    }
    float p0 = 0.0f, p1 = 0.0f, p2 = 0.0f;
    if (lane < 4) {
#pragma unroll
        for (int i = 0; i < 4; ++i) {
            float y = acc[i];
            int j = lane * 4 + i;
            p0 += y * Wcs[j * NCLS + 0];
            p1 += y * Wcs[j * NCLS + 1];
            p2 += y * Wcs[j * NCLS + 2];
        }
    }
    p0 += __shfl_xor(p0, 1); p0 += __shfl_xor(p0, 2);
    p1 += __shfl_xor(p1, 1); p1 += __shfl_xor(p1, 2);
    p2 += __shfl_xor(p2, 1); p2 += __shfl_xor(p2, 2);
    if (lane == 0) {
        float nd = norm_dst[n];
        out[(size_t)n * NCLS + 0] = nd * p0 + Wcs[NH * NCLS + 0];
        out[(size_t)n * NCLS + 1] = nd * p1 + Wcs[NH * NCLS + 1];
        out[(size_t)n * NCLS + 2] = nd * p2 + Wcs[NH * NCLS + 2];
    }
}

// ---------------- launch ----------------
extern "C" void kernel_launch(void* const* d_in, const int* in_sizes, int n_in,
                              void* d_out, int out_size, void* d_ws, size_t ws_size,
                              hipStream_t stream) {
    const float* feat = (const float*)d_in[0];
    const int*   src  = (const int*)d_in[1];
    const int*   dst  = (const int*)d_in[2];
    const float* W1   = (const float*)d_in[3];
    const float* b1   = (const float*)d_in[4];
    const float* W2   = (const float*)d_in[5];
    const float* b2   = (const float*)d_in[6];
    const float* Wfc  = (const float*)d_in[7];
    const float* bfc  = (const float*)d_in[8];
    float* out = (float*)d_out;

    char* ws = (char*)d_ws;
    size_t off = 0;
    auto carve = [&](size_t bytes) {
        char* p = ws + off;
        off = (off + bytes + 255) & ~(size_t)255;
        return p;
    };
    int*   deg_out  = (int*)carve((size_t)N_NODES * 4);
    int*   gcursor  = (int*)carve((size_t)NB * 4);
    int*   csr_base = (int*)carve((size_t)NB * 4);
    int*   pairbuf  = (int*)carve((size_t)NB * BCAP * 4);
    int*   row_ptr  = (int*)carve((size_t)(N_NODES + 1) * 4);
    int*   col      = (int*)carve((size_t)N_EDGES * 4);
    float* norm_dst = (float*)carve((size_t)N_NODES * 4);
    unsigned short* h1b  = (unsigned short*)carve((size_t)N_NODES * NH * 2);
    unsigned short* x1nb = (unsigned short*)carve((size_t)N_NODES * NH * 2);
    unsigned short* W1B  = (unsigned short*)carve(16 * 64 * 8 * 2);
    float* Wc       = (float*)carve((NH * NCLS + NCLS) * 4);
    (void)ws_size;

    hipMemsetAsync(deg_out, 0, (size_t)N_NODES * 4, stream);
    hipMemsetAsync(gcursor, 0, (size_t)NB * 4, stream);

    const int nBinBlocks = (N_EDGES + CHUNK - 1) / CHUNK;   // 196
    bin_kernel<<<nBinBlocks, 512, 0, stream>>>(src, dst, deg_out, gcursor, pairbuf);
    bucket_scan_kernel<<<1, 1024, 0, stream>>>(gcursor, csr_base);
    bucket_csr_kernel<<<NB, 256, 0, stream>>>(gcursor, csr_base, pairbuf, col, row_ptr, norm_dst);

    w1b_prep_kernel<<<32, 256, 0, stream>>>(W1, W1B);
    wc_prep_kernel<<<1, 64, 0, stream>>>(W2, b2, Wfc, bfc, Wc);

    gemm1_kernel<<<1250, 256, 0, stream>>>(feat, W1B, deg_out, h1b);

    agg1_kernel<<<N_NODES / 4, 256, 0, stream>>>(row_ptr, col, h1b, norm_dst, deg_out, b1, x1nb);

    agg2_kernel<<<N_NODES / 4, 256, 0, stream>>>(row_ptr, col, x1nb, norm_dst, Wc, out);
}